// Round 18
// baseline (31.153 us; speedup 1.0000x reference)
//
#include <hip/hip_runtime.h>
#include <math.h>

#define BS   64
#define NW   8
#define NK   10
#define NP   16
#define NT   20
#define NN   4096
#define NTH  512
#define NWAVES (NTH / 64)
#define EPT  (NN / NTH)               // 8 negatives per thread, register-resident
#define NBINS 4096                    // uniform bins over dd in [0, 8): key = dd*512
#define DSCALE 512.0f
#define HP(i) ((i) + ((i) >> 3))      // padded addr: stride-9 rank reads, conflict-free
#define HISTPAD (NBINS + NBINS / 8)
#define CANDMAX 256
#define LOG2PI 1.8378770664093453f
#define LOG2E  1.4426950408889634f
#define LN2    0.6931471805599453f

__device__ __constant__ int d_wpix[NW] = {0, 2, 4, 6, 9, 12, 15, 19};

__global__ __launch_bounds__(NTH, 4) void mdn_row_kernel(
    const float* __restrict__ mu,
    const float* __restrict__ sigma,
    const float* __restrict__ pi,
    const float* __restrict__ neg,
    const float* __restrict__ pos,
    const int* __restrict__ p_wh,
    const int* __restrict__ p_cap,
    float* __restrict__ rowres,
    unsigned int* __restrict__ cnt,
    float* __restrict__ out)
{
    __shared__ unsigned int s_hist[HISTPAD];         // 18KB; reused as sel arrays after select
    __shared__ unsigned long long s_cand[CANDMAX];   // 2KB boundary-bin candidates (full bits + idx)
    __shared__ float s_posx[NP], s_posy[NP];
    __shared__ float s_mu0[NK], s_mu1[NK], s_is0[NK], s_is1[NK], s_ck2[NK];
    __shared__ unsigned int s_wsum[NWAVES];
    __shared__ float s_red[2 * NWAVES];
    __shared__ unsigned long long s_P64;
    __shared__ unsigned int s_bucket, s_below, s_candcnt;

    const int row  = blockIdx.x;      // 0 .. BS*NW-1
    const int b    = row / NW;
    const int w    = row % NW;
    const int tid  = threadIdx.x;
    const int lane = tid & 63;
    const int wid  = tid >> 6;

    // ---------- issue negative loads first (latency hides under init) ----------
    const float2* negp = (const float2*)(neg + (size_t)b * NN * 2);
    float nx[EPT], ny[EPT];
    #pragma unroll
    for (int c = 0; c < EPT; ++c) {
        float2 v = negp[c * NTH + tid];
        nx[c] = v.x; ny[c] = v.y;
    }
    const int cap = *p_cap;
    const int wh  = *p_wh;

    // ---------- phase 0: zero hist, stage positives, mixture constants ----------
    for (int i = tid; i < HISTPAD; i += NTH) s_hist[i] = 0;
    if (tid < NP) {
        const float* pp = pos + (((size_t)b * NP + tid) * NT + d_wpix[w]) * 2;
        s_posx[tid] = pp[0];
        s_posy[tid] = pp[1];
    }
    if (tid >= 64 && tid < 64 + NK) {          // wave 1: per-component precompute
        const int k = tid - 64;
        const float* pib = pi    + ((size_t)b * NW + w) * NK;
        const float* mub = mu    + ((size_t)b * NW + w) * NK * 2;
        const float* sgb = sigma + ((size_t)b * NW + w) * NK * 2;
        float m = pib[0];
        for (int j = 1; j < NK; ++j) m = fmaxf(m, pib[j]);
        float se = 0.f;
        for (int j = 0; j < NK; ++j) se += __expf(pib[j] - m);
        float lse = m + __logf(se);
        float s0 = sgb[2 * k], s1 = sgb[2 * k + 1];
        s_mu0[k] = mub[2 * k];
        s_mu1[k] = mub[2 * k + 1];
        s_is0[k] = 1.0f / s0;
        s_is1[k] = 1.0f / s1;
        s_ck2[k] = ((pib[k] - lse) - __logf(s0) - __logf(s1) - LOG2PI) * LOG2E;
    }
    if (tid == 32) s_candcnt = 0;
    __syncthreads();                                           // B1

    float px[NP], py[NP];
    #pragma unroll
    for (int p = 0; p < NP; ++p) { px[p] = s_posx[p]; py[p] = s_posy[p]; }

    // ---------- phase 1: distances + UNIFORM-quantized histogram ----------
    // key = min(4095, dd*512) is monotone in dd -> selection semantics unchanged;
    // spreads ~4096 values over ~1000+ bins (hot-bin atomic chain ~40, not ~600).
    unsigned int ub[EPT];
    int key[EPT];
    #pragma unroll
    for (int c = 0; c < EPT; ++c) {
        float best0 = INFINITY, best1 = INFINITY;   // pairwise tree halves dep chain
        #pragma unroll
        for (int p = 0; p < NP; p += 2) {
            float dx0 = px[p] - nx[c],     dy0 = py[p] - ny[c];
            float dx1 = px[p + 1] - nx[c], dy1 = py[p + 1] - ny[c];
            best0 = fminf(best0, fmaf(dx0, dx0, dy0 * dy0));
            best1 = fminf(best1, fmaf(dx1, dx1, dy1 * dy1));
        }
        float dd = sqrtf(fminf(best0, best1));      // sqrt(min) == min(sqrt)
        ub[c]  = __float_as_uint(dd);
        key[c] = min(NBINS - 1, (int)(dd * DSCALE));
        atomicAdd(&s_hist[HP(key[c])], 1u);
    }
    __syncthreads();                                           // B2 (hist complete)

    const bool do_sel = (cap > 0 && cap < NN);
    float accZ = 0.f, accS = 0.f;

    if (do_sel) {
        // ---------- phase 2: rank over 4096 bins (stride-9 padded, conflict-free) ----------
        const int base = tid * 8;
        unsigned int hv[8];
        unsigned int cnt8 = 0;
        #pragma unroll
        for (int j = 0; j < 8; ++j) { hv[j] = s_hist[HP(base + j)]; cnt8 += hv[j]; }
        unsigned int v = cnt8;
        #pragma unroll
        for (int off = 1; off < 64; off <<= 1) {
            unsigned int o = __shfl_up(v, off, 64);
            if (lane >= off) v += o;
        }
        if (lane == 63) s_wsum[wid] = v;
        __syncthreads();                                       // B3
        unsigned int wbase = 0;
        for (int i = 0; i < wid; ++i) wbase += s_wsum[i];
        const unsigned int incl = v + wbase;
        const unsigned int excl = incl - cnt8;
        const unsigned int capu = (unsigned int)cap;
        if (excl < capu && capu <= incl) {
            unsigned int run = excl;
            #pragma unroll
            for (int j = 0; j < 8; ++j) {
                unsigned int c2 = hv[j];
                if (capu <= run + c2) { s_bucket = (unsigned int)(base + j); s_below = run; break; }
                run += c2;
            }
        }
        __syncthreads();                                       // B4
        const int B = (int)s_bucket;

        // ---------- phase 3: compact boundary-bin candidates (C ~ 3-10: plain atomics) ----------
        #pragma unroll
        for (int c = 0; c < EPT; ++c) {
            if (key[c] == B) {
                unsigned int p0 = atomicAdd(&s_candcnt, 1u);
                if (p0 < CANDMAX)
                    s_cand[p0] = ((unsigned long long)ub[c] << 20) |
                                 (unsigned long long)(c * NTH + tid);
            }
        }
        __syncthreads();                                       // B5

        // ---------- phase 4: exact rank among candidates (full-bit keys, distinct) ----------
        const int C = (int)min(s_candcnt, (unsigned int)CANDMAX);
        const int remT = cap - (int)s_below;    // how many to take from bin B
        for (int i = tid; i < C; i += NTH) {
            unsigned long long pv = s_cand[i];
            int less = 0;
            for (int j = 0; j < C; ++j) less += (s_cand[j] < pv) ? 1 : 0;
            if (less == remT - 1) s_P64 = pv;   // the remT-th smallest (bits,idx)
        }
        __syncthreads();                                       // B6
        const unsigned long long P = s_P64;

        // ---------- phase 5: per-thread select, scan, compact (x,y,weight) ----------
        int cs = 0;
        bool selv[EPT];
        #pragma unroll
        for (int c = 0; c < EPT; ++c) {
            unsigned long long K = ((unsigned long long)ub[c] << 20) |
                                   (unsigned long long)(c * NTH + tid);
            bool s = (key[c] < B) || (key[c] == B && K <= P);
            selv[c] = s;
            cs += s ? 1 : 0;
        }
        unsigned int v2 = (unsigned int)cs;
        #pragma unroll
        for (int off = 1; off < 64; off <<= 1) {
            unsigned int o = __shfl_up(v2, off, 64);
            if (lane >= off) v2 += o;
        }
        if (lane == 63) s_wsum[wid] = v2;
        __syncthreads();                                       // B7
        unsigned int wb2 = 0;
        for (int i = 0; i < wid; ++i) wb2 += s_wsum[i];
        int wpos = (int)(v2 + wb2) - cs;
        float* selx = (float*)&s_hist[0];
        float* sely = (float*)&s_hist[1024];
        float* sele = (float*)&s_hist[2048];
        #pragma unroll
        for (int c = 0; c < EPT; ++c) {
            if (selv[c]) {
                float dd = __uint_as_float(ub[c]);
                selx[wpos] = wh ? ny[c] : nx[c];
                sely[wpos] = wh ? nx[c] : ny[c];
                sele[wpos] = exp2f(-dd * LOG2E);     // exp(dmin) cancels in S/Z
                ++wpos;
            }
        }
        __syncthreads();                                       // B8

        // ---------- phase 6: dense mixture over the cap selected ----------
        for (int i = tid; i < cap; i += NTH) {
            const float x0 = selx[i], x1 = sely[i], e = sele[i];
            float a[NK];
            #pragma unroll
            for (int k = 0; k < NK; ++k) {
                float z0 = (x0 - s_mu0[k]) * s_is0[k];
                float z1 = (x1 - s_mu1[k]) * s_is1[k];
                float q  = fmaf(z0, z0, z1 * z1);
                a[k] = fmaf(q, -0.5f * LOG2E, s_ck2[k]);
            }
            float t0 = fmaxf(a[0], a[1]), t1 = fmaxf(a[2], a[3]);
            float t2 = fmaxf(a[4], a[5]), t3 = fmaxf(a[6], a[7]);
            float m2 = fmaxf(fmaxf(fmaxf(t0, t1), fmaxf(t2, t3)), fmaxf(a[8], a[9]));
            float se = 0.f;
            #pragma unroll
            for (int k = 0; k < NK; ++k) se += exp2f(a[k] - m2);
            float lp = LN2 * (m2 + log2f(se));
            accZ += e;
            accS += e * lp;
        }
    } else {
        // cold path (cap covers all): direct register walk, no compaction
        #pragma unroll
        for (int c = 0; c < EPT; ++c) {
            const float x0 = wh ? ny[c] : nx[c];
            const float x1 = wh ? nx[c] : ny[c];
            const float e  = exp2f(-__uint_as_float(ub[c]) * LOG2E);
            float a[NK];
            #pragma unroll
            for (int k = 0; k < NK; ++k) {
                float z0 = (x0 - s_mu0[k]) * s_is0[k];
                float z1 = (x1 - s_mu1[k]) * s_is1[k];
                float q  = fmaf(z0, z0, z1 * z1);
                a[k] = fmaf(q, -0.5f * LOG2E, s_ck2[k]);
            }
            float t0 = fmaxf(a[0], a[1]), t1 = fmaxf(a[2], a[3]);
            float t2 = fmaxf(a[4], a[5]), t3 = fmaxf(a[6], a[7]);
            float m2 = fmaxf(fmaxf(fmaxf(t0, t1), fmaxf(t2, t3)), fmaxf(a[8], a[9]));
            float se = 0.f;
            #pragma unroll
            for (int k = 0; k < NK; ++k) se += exp2f(a[k] - m2);
            float lp = LN2 * (m2 + log2f(se));
            accZ += e;
            accS += e * lp;
        }
    }

    // ---------- block reduction + fused fan-in finalize (device-scope atomics) ----------
    #pragma unroll
    for (int off = 32; off; off >>= 1) {
        accZ += __shfl_down(accZ, off, 64);
        accS += __shfl_down(accS, off, 64);
    }
    if (lane == 0) { s_red[wid] = accZ; s_red[NWAVES + wid] = accS; }
    __syncthreads();                                           // B9
    if (tid == 0) {
        float Z = 0.f, S = 0.f;
        for (int i = 0; i < NWAVES; ++i) { Z += s_red[i]; S += s_red[NWAVES + i]; }
        // release-store my row result at device scope (coherent across XCDs)
        __hip_atomic_store(&rowres[row], S / Z, __ATOMIC_RELEASE, __HIP_MEMORY_SCOPE_AGENT);
        // ticket: fires once per batch per launch for ANY starting counter value
        // (8 consecutive increments contain exactly one old&7==7), so no reset/memset
        // is needed and graph replays stay deterministic.
        unsigned int old = __hip_atomic_fetch_add(&cnt[b], 1u, __ATOMIC_ACQ_REL,
                                                  __HIP_MEMORY_SCOPE_AGENT);
        if ((old & (NW - 1)) == (NW - 1)) {    // last of the 8 waypoint blocks
            float s = 0.f;
            #pragma unroll
            for (int j = 0; j < NW; ++j)       // fixed order: bit-deterministic sum
                s += __hip_atomic_load(&rowres[b * NW + j], __ATOMIC_ACQUIRE,
                                       __HIP_MEMORY_SCOPE_AGENT);
            out[b] = -s * (1.0f / NW);
        }
    }
}

extern "C" void kernel_launch(void* const* d_in, const int* in_sizes, int n_in,
                              void* d_out, int out_size, void* d_ws, size_t ws_size,
                              hipStream_t stream)
{
    const float* mu    = (const float*)d_in[0];
    const float* sigma = (const float*)d_in[1];
    const float* pi    = (const float*)d_in[2];
    const float* neg   = (const float*)d_in[3];
    const float* pos   = (const float*)d_in[4];
    const int*   wh    = (const int*)d_in[5];
    const int*   cap   = (const int*)d_in[6];
    float* rowres     = (float*)d_ws;                            // 512 floats
    unsigned int* cnt = (unsigned int*)((char*)d_ws + 2048);     // 64 tickets (no reset needed)
    float* out        = (float*)d_out;

    mdn_row_kernel<<<BS * NW, NTH, 0, stream>>>(mu, sigma, pi, neg, pos, wh, cap,
                                                rowres, cnt, out);
}

// Round 19
// 19.606 us; speedup vs baseline: 1.5889x; 1.5889x over previous
//
#include <hip/hip_runtime.h>
#include <math.h>

#define BS   64
#define NW   8
#define NK   10
#define NP   16
#define NT   20
#define NN   4096
#define NTH  512
#define NWAVES (NTH / 64)
#define EPT  (NN / NTH)               // 8 negatives per thread, register-resident
#define NBINS 4096                    // uniform bins over dd in [0, 8): key = dd*512
#define DSCALE 512.0f
#define HP(i) ((i) + ((i) >> 3))      // padded addr: stride-9 rank reads, conflict-free
#define HISTPAD (NBINS + NBINS / 8)
#define CANDMAX 256
#define LOG2PI 1.8378770664093453f
#define LOG2E  1.4426950408889634f
#define LN2    0.6931471805599453f

__device__ __constant__ int d_wpix[NW] = {0, 2, 4, 6, 9, 12, 15, 19};

__global__ __launch_bounds__(NTH, 4) void mdn_row_kernel(
    const float* __restrict__ mu,
    const float* __restrict__ sigma,
    const float* __restrict__ pi,
    const float* __restrict__ neg,
    const float* __restrict__ pos,
    const int* __restrict__ p_wh,
    const int* __restrict__ p_cap,
    float* __restrict__ rowres)
{
    __shared__ unsigned int s_hist[HISTPAD];         // 18KB; reused as sel arrays after select
    __shared__ unsigned long long s_cand[CANDMAX];   // 2KB boundary-bin candidates (full bits + idx)
    __shared__ float s_posx[NP], s_posy[NP];
    __shared__ float s_mu0[NK], s_mu1[NK], s_is0[NK], s_is1[NK], s_ck2[NK];
    __shared__ unsigned int s_wsum[NWAVES];
    __shared__ float s_red[2 * NWAVES];
    __shared__ unsigned long long s_P64;
    __shared__ unsigned int s_bucket, s_below, s_candcnt;

    const int row  = blockIdx.x;      // 0 .. BS*NW-1
    const int b    = row / NW;
    const int w    = row % NW;
    const int tid  = threadIdx.x;
    const int lane = tid & 63;
    const int wid  = tid >> 6;

    // ---------- issue negative loads first (latency hides under init) ----------
    const float2* negp = (const float2*)(neg + (size_t)b * NN * 2);
    float nx[EPT], ny[EPT];
    #pragma unroll
    for (int c = 0; c < EPT; ++c) {
        float2 v = negp[c * NTH + tid];
        nx[c] = v.x; ny[c] = v.y;
    }
    const int cap = *p_cap;
    const int wh  = *p_wh;

    // ---------- phase 0: zero hist, stage positives, mixture constants ----------
    for (int i = tid; i < HISTPAD; i += NTH) s_hist[i] = 0;
    if (tid < NP) {
        const float* pp = pos + (((size_t)b * NP + tid) * NT + d_wpix[w]) * 2;
        s_posx[tid] = pp[0];
        s_posy[tid] = pp[1];
    }
    if (tid >= 64 && tid < 64 + NK) {          // wave 1: per-component precompute
        const int k = tid - 64;
        const float* pib = pi    + ((size_t)b * NW + w) * NK;
        const float* mub = mu    + ((size_t)b * NW + w) * NK * 2;
        const float* sgb = sigma + ((size_t)b * NW + w) * NK * 2;
        float m = pib[0];
        for (int j = 1; j < NK; ++j) m = fmaxf(m, pib[j]);
        float se = 0.f;
        for (int j = 0; j < NK; ++j) se += __expf(pib[j] - m);
        float lse = m + __logf(se);
        float s0 = sgb[2 * k], s1 = sgb[2 * k + 1];
        s_mu0[k] = mub[2 * k];
        s_mu1[k] = mub[2 * k + 1];
        s_is0[k] = 1.0f / s0;
        s_is1[k] = 1.0f / s1;
        s_ck2[k] = ((pib[k] - lse) - __logf(s0) - __logf(s1) - LOG2PI) * LOG2E;
    }
    if (tid == 32) s_candcnt = 0;
    __syncthreads();                                           // B1

    float px[NP], py[NP];
    #pragma unroll
    for (int p = 0; p < NP; ++p) { px[p] = s_posx[p]; py[p] = s_posy[p]; }

    // ---------- phase 1: distances + UNIFORM-quantized histogram ----------
    // key = min(4095, dd*512) is monotone in dd -> selection semantics unchanged;
    // spreads ~4096 values over ~1000+ bins (hot-bin atomic chain ~40, not ~600).
    unsigned int ub[EPT];
    int key[EPT];
    #pragma unroll
    for (int c = 0; c < EPT; ++c) {
        float best0 = INFINITY, best1 = INFINITY;   // pairwise tree halves dep chain
        #pragma unroll
        for (int p = 0; p < NP; p += 2) {
            float dx0 = px[p] - nx[c],     dy0 = py[p] - ny[c];
            float dx1 = px[p + 1] - nx[c], dy1 = py[p + 1] - ny[c];
            best0 = fminf(best0, fmaf(dx0, dx0, dy0 * dy0));
            best1 = fminf(best1, fmaf(dx1, dx1, dy1 * dy1));
        }
        float dd = sqrtf(fminf(best0, best1));      // sqrt(min) == min(sqrt)
        ub[c]  = __float_as_uint(dd);
        key[c] = min(NBINS - 1, (int)(dd * DSCALE));
        atomicAdd(&s_hist[HP(key[c])], 1u);
    }
    __syncthreads();                                           // B2 (hist complete)

    const bool do_sel = (cap > 0 && cap < NN);
    float accZ = 0.f, accS = 0.f;

    if (do_sel) {
        // ---------- phase 2: rank over 4096 bins (stride-9 padded, conflict-free) ----------
        const int base = tid * 8;
        unsigned int hv[8];
        unsigned int cnt8 = 0;
        #pragma unroll
        for (int j = 0; j < 8; ++j) { hv[j] = s_hist[HP(base + j)]; cnt8 += hv[j]; }
        unsigned int v = cnt8;
        #pragma unroll
        for (int off = 1; off < 64; off <<= 1) {
            unsigned int o = __shfl_up(v, off, 64);
            if (lane >= off) v += o;
        }
        if (lane == 63) s_wsum[wid] = v;
        __syncthreads();                                       // B3
        unsigned int wbase = 0;
        for (int i = 0; i < wid; ++i) wbase += s_wsum[i];
        const unsigned int incl = v + wbase;
        const unsigned int excl = incl - cnt8;
        const unsigned int capu = (unsigned int)cap;
        if (excl < capu && capu <= incl) {
            unsigned int run = excl;
            #pragma unroll
            for (int j = 0; j < 8; ++j) {
                unsigned int c2 = hv[j];
                if (capu <= run + c2) { s_bucket = (unsigned int)(base + j); s_below = run; break; }
                run += c2;
            }
        }
        __syncthreads();                                       // B4
        const int B = (int)s_bucket;

        // ---------- phase 3: compact boundary-bin candidates (C ~ 3-10: plain atomics) ----------
        #pragma unroll
        for (int c = 0; c < EPT; ++c) {
            if (key[c] == B) {
                unsigned int p0 = atomicAdd(&s_candcnt, 1u);
                if (p0 < CANDMAX)
                    s_cand[p0] = ((unsigned long long)ub[c] << 20) |
                                 (unsigned long long)(c * NTH + tid);
            }
        }
        __syncthreads();                                       // B5

        // ---------- phase 4: exact rank among candidates (full-bit keys, distinct) ----------
        const int C = (int)min(s_candcnt, (unsigned int)CANDMAX);
        const int remT = cap - (int)s_below;    // how many to take from bin B
        for (int i = tid; i < C; i += NTH) {
            unsigned long long pv = s_cand[i];
            int less = 0;
            for (int j = 0; j < C; ++j) less += (s_cand[j] < pv) ? 1 : 0;
            if (less == remT - 1) s_P64 = pv;   // the remT-th smallest (bits,idx)
        }
        __syncthreads();                                       // B6
        const unsigned long long P = s_P64;

        // ---------- phase 5: per-thread select, scan, compact (x,y,weight) ----------
        int cs = 0;
        bool selv[EPT];
        #pragma unroll
        for (int c = 0; c < EPT; ++c) {
            unsigned long long K = ((unsigned long long)ub[c] << 20) |
                                   (unsigned long long)(c * NTH + tid);
            bool s = (key[c] < B) || (key[c] == B && K <= P);
            selv[c] = s;
            cs += s ? 1 : 0;
        }
        unsigned int v2 = (unsigned int)cs;
        #pragma unroll
        for (int off = 1; off < 64; off <<= 1) {
            unsigned int o = __shfl_up(v2, off, 64);
            if (lane >= off) v2 += o;
        }
        if (lane == 63) s_wsum[wid] = v2;
        __syncthreads();                                       // B7
        unsigned int wb2 = 0;
        for (int i = 0; i < wid; ++i) wb2 += s_wsum[i];
        int wpos = (int)(v2 + wb2) - cs;
        float* selx = (float*)&s_hist[0];
        float* sely = (float*)&s_hist[1024];
        float* sele = (float*)&s_hist[2048];
        #pragma unroll
        for (int c = 0; c < EPT; ++c) {
            if (selv[c]) {
                float dd = __uint_as_float(ub[c]);
                selx[wpos] = wh ? ny[c] : nx[c];
                sely[wpos] = wh ? nx[c] : ny[c];
                sele[wpos] = exp2f(-dd * LOG2E);     // exp(dmin) cancels in S/Z
                ++wpos;
            }
        }
        __syncthreads();                                       // B8

        // ---------- phase 6: dense mixture over the cap selected ----------
        for (int i = tid; i < cap; i += NTH) {
            const float x0 = selx[i], x1 = sely[i], e = sele[i];
            float a[NK];
            #pragma unroll
            for (int k = 0; k < NK; ++k) {
                float z0 = (x0 - s_mu0[k]) * s_is0[k];
                float z1 = (x1 - s_mu1[k]) * s_is1[k];
                float q  = fmaf(z0, z0, z1 * z1);
                a[k] = fmaf(q, -0.5f * LOG2E, s_ck2[k]);
            }
            float t0 = fmaxf(a[0], a[1]), t1 = fmaxf(a[2], a[3]);
            float t2 = fmaxf(a[4], a[5]), t3 = fmaxf(a[6], a[7]);
            float m2 = fmaxf(fmaxf(fmaxf(t0, t1), fmaxf(t2, t3)), fmaxf(a[8], a[9]));
            float se = 0.f;
            #pragma unroll
            for (int k = 0; k < NK; ++k) se += exp2f(a[k] - m2);
            float lp = LN2 * (m2 + log2f(se));
            accZ += e;
            accS += e * lp;
        }
    } else {
        // cold path (cap covers all): direct register walk, no compaction
        #pragma unroll
        for (int c = 0; c < EPT; ++c) {
            const float x0 = wh ? ny[c] : nx[c];
            const float x1 = wh ? nx[c] : ny[c];
            const float e  = exp2f(-__uint_as_float(ub[c]) * LOG2E);
            float a[NK];
            #pragma unroll
            for (int k = 0; k < NK; ++k) {
                float z0 = (x0 - s_mu0[k]) * s_is0[k];
                float z1 = (x1 - s_mu1[k]) * s_is1[k];
                float q  = fmaf(z0, z0, z1 * z1);
                a[k] = fmaf(q, -0.5f * LOG2E, s_ck2[k]);
            }
            float t0 = fmaxf(a[0], a[1]), t1 = fmaxf(a[2], a[3]);
            float t2 = fmaxf(a[4], a[5]), t3 = fmaxf(a[6], a[7]);
            float m2 = fmaxf(fmaxf(fmaxf(t0, t1), fmaxf(t2, t3)), fmaxf(a[8], a[9]));
            float se = 0.f;
            #pragma unroll
            for (int k = 0; k < NK; ++k) se += exp2f(a[k] - m2);
            float lp = LN2 * (m2 + log2f(se));
            accZ += e;
            accS += e * lp;
        }
    }

    // ---------- block reduction ----------
    #pragma unroll
    for (int off = 32; off; off >>= 1) {
        accZ += __shfl_down(accZ, off, 64);
        accS += __shfl_down(accS, off, 64);
    }
    if (lane == 0) { s_red[wid] = accZ; s_red[NWAVES + wid] = accS; }
    __syncthreads();                                           // B9
    if (tid == 0) {
        float Z = 0.f, S = 0.f;
        for (int i = 0; i < NWAVES; ++i) { Z += s_red[i]; S += s_red[NWAVES + i]; }
        rowres[row] = S / Z;
    }
}

__global__ void mdn_finalize_kernel(const float* __restrict__ rowres,
                                    float* __restrict__ out)
{
    int b = threadIdx.x;
    if (b < BS) {
        float s = 0.f;
        #pragma unroll
        for (int w = 0; w < NW; ++w) s += rowres[b * NW + w];
        out[b] = -s * (1.0f / NW);
    }
}

extern "C" void kernel_launch(void* const* d_in, const int* in_sizes, int n_in,
                              void* d_out, int out_size, void* d_ws, size_t ws_size,
                              hipStream_t stream)
{
    const float* mu    = (const float*)d_in[0];
    const float* sigma = (const float*)d_in[1];
    const float* pi    = (const float*)d_in[2];
    const float* neg   = (const float*)d_in[3];
    const float* pos   = (const float*)d_in[4];
    const int*   wh    = (const int*)d_in[5];
    const int*   cap   = (const int*)d_in[6];
    float* rowres = (float*)d_ws;   // BS*NW floats scratch
    float* out    = (float*)d_out;

    mdn_row_kernel<<<BS * NW, NTH, 0, stream>>>(mu, sigma, pi, neg, pos, wh, cap, rowres);
    mdn_finalize_kernel<<<1, 64, 0, stream>>>(rowres, out);
}